// Round 11
// baseline (62.425 us; speedup 1.0000x reference)
//
#include <hip/hip_runtime.h>

#define NN 32768
#define MM 4096
#define DD 32

typedef short short8 __attribute__((ext_vector_type(8)));
typedef float f32x4 __attribute__((ext_vector_type(4)));

#define ROWTILES 4     // 16-row MFMA tiles per wave -> 64 rows/wave
#define WAVES 4        // waves per block -> 256 rows/block

__device__ __forceinline__ unsigned short f2bf(float f) {
    unsigned u = __float_as_uint(f);
    unsigned r = 0x7FFFu + ((u >> 16) & 1u);
    return (unsigned short)((u + r) >> 16);
}
__device__ __forceinline__ float bf2f(unsigned short h) {
    return __uint_as_float(((unsigned)h) << 16);
}

// ---------------------------------------------------------------------------
// Prep (element-parallel): 4 lanes per row, each handling 8 elements.
// X is PRE-SCALED by LA = log2(e)/g^2 before the bf16 hi/lo split.
// Bx_i = -0.5*LA*||x_i||^2 ; w_j = alpha_j * 2^(-0.5*LA*||y_j||^2).
// ---------------------------------------------------------------------------
__global__ __launch_bounds__(256) void prep_kern(
    const float* __restrict__ X, const float* __restrict__ C,
    const float* __restrict__ alphas, const float* __restrict__ sigma,
    unsigned short* __restrict__ Xh, unsigned short* __restrict__ Xl,
    unsigned short* __restrict__ Ch, unsigned short* __restrict__ Cl,
    float* __restrict__ Bx, float* __restrict__ w)
{
    const int i = blockIdx.x * 256 + threadIdx.x;   // (NN+MM)*4 total
    const int row = i >> 2;
    const int q = i & 3;
    const float g = sigma[0];
    const float LA = 1.44269504088896340736f / (g * g);

    const bool isX = (row < NN);
    const int crow = isX ? row : (row - NN);
    const float* src = (isX ? X + (size_t)row * DD : C + (size_t)crow * DD) + q * 8;
    unsigned short* dh = (isX ? Xh + (size_t)row * DD : Ch + (size_t)crow * DD) + q * 8;
    unsigned short* dl = (isX ? Xl + (size_t)row * DD : Cl + (size_t)crow * DD) + q * 8;
    const float scale = isX ? LA : 1.0f;

    float4 a = ((const float4*)src)[0];
    float4 b = ((const float4*)src)[1];
    float vv[8] = {a.x, a.y, a.z, a.w, b.x, b.y, b.z, b.w};
    float s2 = 0.f;
    short8 hv, lv;
#pragma unroll
    for (int e = 0; e < 8; ++e) {
        float v = vv[e];
        s2 = fmaf(v, v, s2);
        float sv = v * scale;
        unsigned short h = f2bf(sv);
        hv[e] = (short)h;
        lv[e] = (short)f2bf(sv - bf2f(h));
    }
    *(short8*)dh = hv;
    *(short8*)dl = lv;

    // 4-lane row-sum (lanes row*4 .. row*4+3 are contiguous in the wave)
    s2 += __shfl_xor(s2, 1, 64);
    s2 += __shfl_xor(s2, 2, 64);
    if (q == 0) {
        float bb = -0.5f * LA * s2;
        if (isX) Bx[row] = bb;
        else     w[crow] = alphas[crow] * exp2f(bb);
    }
}

// ---------------------------------------------------------------------------
// Main: R10 carrier + branch-free polynomial exp2 epilogue.
// Model (fits R1/R6/R8 counters): v_exp_f32 occupies the issue port ~32
// cy/wave64; R8's poly failed only because ldexpf lowered to branchy ocml
// scalbn. This build replaces exp with 12 full-rate ops/element:
//   t clamped to [-120,120] (med3; in-loop t = LA*(x.y) is within [-45,45]
//   since g=1-scale data, so exponent field is always a valid normal),
//   2^floor(t) built by integer exponent-field construction
//   (((int)ft << 23) + 0x3f800000), deg-5 Horner for 2^frac (same
//   coefficients that PASSED precision in R8, absmax 2.38e-7).
// Magnitude path identical to R10 (proven): acc = sum_j wj*2^t, multiplied
// by 2^Bx once in the store epilogue.
// ---------------------------------------------------------------------------
template <int MS>
__global__ __launch_bounds__(256, 4) void rbf_mfma_lds(
    const unsigned short* __restrict__ Xh, const unsigned short* __restrict__ Xl,
    const unsigned short* __restrict__ Ch, const unsigned short* __restrict__ Cl,
    const float* __restrict__ Bx, const float* __restrict__ w,
    float* __restrict__ part)
{
    constexpr int MPER = MM / MS;
    constexpr int NT = MPER / 16;
    __shared__ unsigned short sCh[MPER * DD];
    __shared__ unsigned short sCl[MPER * DD];
    __shared__ float sw[MPER];

    const int tid = threadIdx.x;
    const int wave = tid >> 6;
    const int lane = tid & 63;
    const int l15 = lane & 15;
    const int lhi = lane >> 4;
    const int rowbase = (blockIdx.x * WAVES + wave) * (16 * ROWTILES);
    const int slice = blockIdx.y;
    const int j0 = slice * MPER;

    const char* lh = (const char*)sCh;
    const char* ll = (const char*)sCl;

    // ---- stage C slice (hi+lo) and w slice into LDS, linear & vectorized ---
    {
        const float4* gh = (const float4*)(Ch + (size_t)j0 * DD);
        const float4* gl = (const float4*)(Cl + (size_t)j0 * DD);
        constexpr int NV = MPER * DD / 8;  // 16B chunks per slab
        for (int o = tid; o < NV; o += 256) {
            ((float4*)sCh)[o] = gh[o];
            ((float4*)sCl)[o] = gl[o];
        }
        if (tid < MPER) sw[tid] = w[j0 + tid];
    }

    // ---- A fragments (hi/lo), loaded while staging is in flight ------------
    short8 ah[ROWTILES], al[ROWTILES];
#pragma unroll
    for (int t = 0; t < ROWTILES; ++t) {
        int r = rowbase + t * 16 + l15;
        ah[t] = *(const short8*)(Xh + (size_t)r * DD + lhi * 8);
        al[t] = *(const short8*)(Xl + (size_t)r * DD + lhi * 8);
    }

    f32x4 acc[ROWTILES];
#pragma unroll
    for (int t = 0; t < ROWTILES; ++t) acc[t] = (f32x4){0.f, 0.f, 0.f, 0.f};

    __syncthreads();

    const int lbase = l15 * 64 + lhi * 16;
    const f32x4 kZero = {0.f, 0.f, 0.f, 0.f};

    // ---- main loop: immediate-offset ds_reads, 3-MFMA double-bf16, poly ----
#pragma unroll 2
    for (int jt = 0; jt < NT; ++jt) {
        short8 bh = *(const short8*)(lh + lbase + jt * 1024);
        short8 bl = *(const short8*)(ll + lbase + jt * 1024);
        float wj = sw[jt * 16 + l15];
#pragma unroll
        for (int t = 0; t < ROWTILES; ++t) {
            f32x4 d;
            d = __builtin_amdgcn_mfma_f32_16x16x32_bf16(ah[t], bl, kZero, 0, 0, 0);
            d = __builtin_amdgcn_mfma_f32_16x16x32_bf16(al[t], bh, d, 0, 0, 0);
            d = __builtin_amdgcn_mfma_f32_16x16x32_bf16(ah[t], bh, d, 0, 0, 0);
#pragma unroll
            for (int rr = 0; rr < 4; ++rr) {
                float tt = fminf(fmaxf(d[rr], -120.f), 120.f);  // v_med3_f32
                float ft = floorf(tt);
                float f  = tt - ft;
                float sc = __int_as_float((((int)ft) << 23) + 0x3f800000);
                float p = fmaf(f, 0.00134581f, 0.00967838f);
                p = fmaf(f, p, 0.05550411f);
                p = fmaf(f, p, 0.24022650f);
                p = fmaf(f, p, 0.69314718f);
                p = fmaf(f, p, 1.0f);
                acc[t][rr] = fmaf(p, wj * sc, acc[t][rr]);
            }
        }
    }

    // ---- reduce over the 16 columns (lane bits 0..3) -----------------------
#pragma unroll
    for (int t = 0; t < ROWTILES; ++t)
#pragma unroll
        for (int rr = 0; rr < 4; ++rr) {
            float v = acc[t][rr];
            v += __shfl_xor(v, 1, 64);
            v += __shfl_xor(v, 2, 64);
            v += __shfl_xor(v, 4, 64);
            v += __shfl_xor(v, 8, 64);
            acc[t][rr] = v;
        }
    // ---- epilogue: apply 2^Bx (row-only) once, store float4 ----------------
    if (l15 == 0) {
#pragma unroll
        for (int t = 0; t < ROWTILES; ++t) {
            float4 bxv = *(const float4*)&Bx[rowbase + t * 16 + lhi * 4];
            f32x4 o;
            o[0] = acc[t][0] * __builtin_amdgcn_exp2f(bxv.x);
            o[1] = acc[t][1] * __builtin_amdgcn_exp2f(bxv.y);
            o[2] = acc[t][2] * __builtin_amdgcn_exp2f(bxv.z);
            o[3] = acc[t][3] * __builtin_amdgcn_exp2f(bxv.w);
            *(f32x4*)&part[(size_t)slice * NN + rowbase + t * 16 + lhi * 4] = o;
        }
    }
}

template <int MS>
__global__ __launch_bounds__(256) void reduce_kern(const float* __restrict__ part,
                                                   float* __restrict__ out) {
    int i = blockIdx.x * 256 + threadIdx.x;
    float s = 0.f;
#pragma unroll
    for (int k = 0; k < MS; ++k) s += part[(size_t)k * NN + i];
    out[i] = s;
}

// ---------------------------------------------------------------------------
// Fallback (round-1 VALU path) in case ws_size is too small.
// ---------------------------------------------------------------------------
__global__ __launch_bounds__(256) void wkern(const float* __restrict__ C,
                                             const float* __restrict__ alphas,
                                             const float* __restrict__ sigma,
                                             float* __restrict__ w) {
    int j = blockIdx.x * 256 + threadIdx.x;
    if (j >= MM) return;
    float g = sigma[0];
    float inv_g2 = 1.0f / (g * g);
    const float4* cp = (const float4*)(C + (size_t)j * DD);
    float y2 = 0.f;
#pragma unroll
    for (int q = 0; q < DD / 4; ++q) {
        float4 v = cp[q];
        y2 = fmaf(v.x, v.x, y2);
        y2 = fmaf(v.y, v.y, y2);
        y2 = fmaf(v.z, v.z, y2);
        y2 = fmaf(v.w, v.w, y2);
    }
    w[j] = alphas[j] * exp2f(-0.5f * inv_g2 * 1.44269504088896340736f * y2);
}

__global__ __launch_bounds__(128) void rbf_valu(const float* __restrict__ X,
                                                const float* __restrict__ C,
                                                const float* __restrict__ w,
                                                const float* __restrict__ sigma,
                                                float* __restrict__ out) {
    const int row = blockIdx.x * 128 + threadIdx.x;
    const float g = sigma[0];
    const float A = 1.44269504088896340736f / (g * g);
    float x[DD];
    const float4* xp = (const float4*)(X + (size_t)row * DD);
#pragma unroll
    for (int q = 0; q < DD / 4; ++q) {
        float4 v = xp[q];
        x[4 * q + 0] = v.x; x[4 * q + 1] = v.y;
        x[4 * q + 2] = v.z; x[4 * q + 3] = v.w;
    }
    float x2 = 0.f;
#pragma unroll
    for (int d = 0; d < DD; ++d) x2 = fmaf(x[d], x[d], x2);
    const float B = -0.5f * A * x2;
    float acc = 0.f;
#pragma unroll 2
    for (int j = 0; j < MM; ++j) {
        const float* cj = C + (size_t)j * DD;
        float d0 = 0.f, d1 = 0.f, d2 = 0.f, d3 = 0.f;
#pragma unroll
        for (int d = 0; d < DD; d += 4) {
            d0 = fmaf(cj[d + 0], x[d + 0], d0);
            d1 = fmaf(cj[d + 1], x[d + 1], d1);
            d2 = fmaf(cj[d + 2], x[d + 2], d2);
            d3 = fmaf(cj[d + 3], x[d + 3], d3);
        }
        float dot = (d0 + d1) + (d2 + d3);
        acc = fmaf(w[j], exp2f(fmaf(dot, A, B)), acc);
    }
    out[row] = acc;
}

extern "C" void kernel_launch(void* const* d_in, const int* in_sizes, int n_in,
                              void* d_out, int out_size, void* d_ws, size_t ws_size,
                              hipStream_t stream) {
    const float* X  = (const float*)d_in[0];
    const float* C  = (const float*)d_in[1];
    const float* al = (const float*)d_in[2];
    const float* sg = (const float*)d_in[3];
    float* out = (float*)d_out;

    // Workspace layout (all 16B aligned).
    size_t off = 0;
    unsigned short* Xh = (unsigned short*)((char*)d_ws + off); off += (size_t)NN * DD * 2;
    unsigned short* Xl = (unsigned short*)((char*)d_ws + off); off += (size_t)NN * DD * 2;
    unsigned short* Ch = (unsigned short*)((char*)d_ws + off); off += (size_t)MM * DD * 2;
    unsigned short* Cl = (unsigned short*)((char*)d_ws + off); off += (size_t)MM * DD * 2;
    float* Bx = (float*)((char*)d_ws + off); off += (size_t)NN * 4;
    float* w  = (float*)((char*)d_ws + off); off += (size_t)MM * 4;
    float* part = (float*)((char*)d_ws + off);
    const size_t base = off;

    const size_t need32 = base + (size_t)32 * NN * 4;
    const size_t need8  = base + (size_t)8 * NN * 4;

    if (ws_size >= need8) {
        prep_kern<<<(NN + MM) * 4 / 256, 256, 0, stream>>>(X, C, al, sg, Xh, Xl, Ch, Cl, Bx, w);
        if (ws_size >= need32) {
            dim3 grid(NN / (WAVES * 16 * ROWTILES), 32);
            rbf_mfma_lds<32><<<grid, 64 * WAVES, 0, stream>>>(Xh, Xl, Ch, Cl, Bx, w, part);
            reduce_kern<32><<<NN / 256, 256, 0, stream>>>(part, out);
        } else {
            dim3 grid(NN / (WAVES * 16 * ROWTILES), 8);
            rbf_mfma_lds<8><<<grid, 64 * WAVES, 0, stream>>>(Xh, Xl, Ch, Cl, Bx, w, part);
            reduce_kern<8><<<NN / 256, 256, 0, stream>>>(part, out);
        }
    } else {
        // Fallback: fp32 VALU path, needs only 16 KB for w.
        float* wf = (float*)d_ws;
        wkern<<<MM / 256, 256, 0, stream>>>(C, al, sg, wf);
        rbf_valu<<<NN / 128, 128, 0, stream>>>(X, C, wf, sg, out);
    }
}

// Round 12
// 42.262 us; speedup vs baseline: 1.4771x; 1.4771x over previous
//
#include <hip/hip_runtime.h>

#define NN 32768
#define MM 4096
#define DD 32

typedef short short8 __attribute__((ext_vector_type(8)));
typedef float f32x4 __attribute__((ext_vector_type(4)));

#define ROWTILES 4     // 16-row MFMA tiles per wave -> 64 rows/wave
#define WAVES 4        // waves per block -> 256 rows/block

__device__ __forceinline__ unsigned short f2bf(float f) {
    unsigned u = __float_as_uint(f);
    unsigned r = 0x7FFFu + ((u >> 16) & 1u);
    return (unsigned short)((u + r) >> 16);
}
__device__ __forceinline__ float bf2f(unsigned short h) {
    return __uint_as_float(((unsigned)h) << 16);
}

// ---------------------------------------------------------------------------
// Prep (element-parallel): 4 lanes per row, each handling 8 elements.
// X is PRE-SCALED by LA = log2(e)/g^2 before the bf16 hi/lo split.
// Bx_i = -0.5*LA*||x_i||^2 ; w_j = alpha_j * 2^(-0.5*LA*||y_j||^2).
// ---------------------------------------------------------------------------
__global__ __launch_bounds__(256) void prep_kern(
    const float* __restrict__ X, const float* __restrict__ C,
    const float* __restrict__ alphas, const float* __restrict__ sigma,
    unsigned short* __restrict__ Xh, unsigned short* __restrict__ Xl,
    unsigned short* __restrict__ Ch, unsigned short* __restrict__ Cl,
    float* __restrict__ Bx, float* __restrict__ w)
{
    const int i = blockIdx.x * 256 + threadIdx.x;   // (NN+MM)*4 total
    const int row = i >> 2;
    const int q = i & 3;
    const float g = sigma[0];
    const float LA = 1.44269504088896340736f / (g * g);

    const bool isX = (row < NN);
    const int crow = isX ? row : (row - NN);
    const float* src = (isX ? X + (size_t)row * DD : C + (size_t)crow * DD) + q * 8;
    unsigned short* dh = (isX ? Xh + (size_t)row * DD : Ch + (size_t)crow * DD) + q * 8;
    unsigned short* dl = (isX ? Xl + (size_t)row * DD : Cl + (size_t)crow * DD) + q * 8;
    const float scale = isX ? LA : 1.0f;

    float4 a = ((const float4*)src)[0];
    float4 b = ((const float4*)src)[1];
    float vv[8] = {a.x, a.y, a.z, a.w, b.x, b.y, b.z, b.w};
    float s2 = 0.f;
    short8 hv, lv;
#pragma unroll
    for (int e = 0; e < 8; ++e) {
        float v = vv[e];
        s2 = fmaf(v, v, s2);
        float sv = v * scale;
        unsigned short h = f2bf(sv);
        hv[e] = (short)h;
        lv[e] = (short)f2bf(sv - bf2f(h));
    }
    *(short8*)dh = hv;
    *(short8*)dl = lv;

    // 4-lane row-sum (lanes row*4 .. row*4+3 are contiguous in the wave)
    s2 += __shfl_xor(s2, 1, 64);
    s2 += __shfl_xor(s2, 2, 64);
    if (q == 0) {
        float bb = -0.5f * LA * s2;
        if (isX) Bx[row] = bb;
        else     w[crow] = alphas[crow] * exp2f(bb);
    }
}

// ---------------------------------------------------------------------------
// Main: R10 carrier + 1-deep SOFTWARE PIPELINE to overlap the MFMA and VALU
// pipes. Diagnosis (R6 PMC): MfmaUtil 37.5 + VALUBusy 59 ~= 96% -- the pipes
// were perfectly ANTI-correlated (wall = MFMA-busy + VALU-busy serially),
// because each jt's chain (3xMFMA -> exp -> fmac) forces phase alternation
// and lockstep waves never desync. Fix: unroll-by-2 with statically named
// A/B register sets (no runtime indexing -> no scratch, no rotation movs):
//   ... read(k+2) ; MFMA(k+1 -> dB) ; EPI(k from dA) ; ...
// so the 12 MFMAs of jt k+1 execute UNDER the 32-op VALU epilogue of jt k.
// VGPR ~130 -> __launch_bounds__(256,3). Numerics identical to R10
// (exp2+fmac epilogue, 2^Bx applied once at store; absmax 2.38e-7 proven).
// ---------------------------------------------------------------------------
template <int MS>
__global__ __launch_bounds__(256, 3) void rbf_mfma_lds(
    const unsigned short* __restrict__ Xh, const unsigned short* __restrict__ Xl,
    const unsigned short* __restrict__ Ch, const unsigned short* __restrict__ Cl,
    const float* __restrict__ Bx, const float* __restrict__ w,
    float* __restrict__ part)
{
    constexpr int MPER = MM / MS;
    constexpr int NT = MPER / 16;
    static_assert((NT & 1) == 0, "NT must be even for the A/B pipeline");
    __shared__ unsigned short sCh[MPER * DD];
    __shared__ unsigned short sCl[MPER * DD];
    __shared__ float sw[MPER];

    const int tid = threadIdx.x;
    const int wave = tid >> 6;
    const int lane = tid & 63;
    const int l15 = lane & 15;
    const int lhi = lane >> 4;
    const int rowbase = (blockIdx.x * WAVES + wave) * (16 * ROWTILES);
    const int slice = blockIdx.y;
    const int j0 = slice * MPER;

    const char* lh = (const char*)sCh;
    const char* ll = (const char*)sCl;

    // ---- stage C slice (hi+lo) and w slice into LDS, linear & vectorized ---
    {
        const float4* gh = (const float4*)(Ch + (size_t)j0 * DD);
        const float4* gl = (const float4*)(Cl + (size_t)j0 * DD);
        constexpr int NV = MPER * DD / 8;  // 16B chunks per slab
        for (int o = tid; o < NV; o += 256) {
            ((float4*)sCh)[o] = gh[o];
            ((float4*)sCl)[o] = gl[o];
        }
        if (tid < MPER) sw[tid] = w[j0 + tid];
    }

    // ---- A fragments (hi/lo), loaded while staging is in flight ------------
    short8 ah[ROWTILES], al[ROWTILES];
#pragma unroll
    for (int t = 0; t < ROWTILES; ++t) {
        int r = rowbase + t * 16 + l15;
        ah[t] = *(const short8*)(Xh + (size_t)r * DD + lhi * 8);
        al[t] = *(const short8*)(Xl + (size_t)r * DD + lhi * 8);
    }

    f32x4 acc[ROWTILES];
#pragma unroll
    for (int t = 0; t < ROWTILES; ++t) acc[t] = (f32x4){0.f, 0.f, 0.f, 0.f};

    __syncthreads();

    const int lbase = l15 * 64 + lhi * 16;
    const f32x4 kZero = {0.f, 0.f, 0.f, 0.f};

#define READB(k, BH, BL, WJ)                                   \
    do {                                                        \
        BH = *(const short8*)(lh + lbase + (k) * 1024);         \
        BL = *(const short8*)(ll + lbase + (k) * 1024);         \
        WJ = sw[(k) * 16 + l15];                                \
    } while (0)

#define MFMAJT(BH, BL, D)                                                        \
    do {                                                                          \
        _Pragma("unroll")                                                         \
        for (int t = 0; t < ROWTILES; ++t) {                                      \
            f32x4 dd;                                                             \
            dd = __builtin_amdgcn_mfma_f32_16x16x32_bf16(ah[t], BL, kZero, 0, 0, 0); \
            dd = __builtin_amdgcn_mfma_f32_16x16x32_bf16(al[t], BH, dd, 0, 0, 0); \
            dd = __builtin_amdgcn_mfma_f32_16x16x32_bf16(ah[t], BH, dd, 0, 0, 0); \
            D[t] = dd;                                                            \
        }                                                                         \
    } while (0)

#define EPILOG(D, WJ)                                                             \
    do {                                                                          \
        _Pragma("unroll")                                                         \
        for (int t = 0; t < ROWTILES; ++t)                                        \
            _Pragma("unroll")                                                     \
            for (int rr = 0; rr < 4; ++rr)                                        \
                acc[t][rr] = fmaf(WJ, __builtin_amdgcn_exp2f(D[t][rr]), acc[t][rr]); \
    } while (0)

    // ---- pipelined main loop: MFMA(jt+1) overlaps EPILOG(jt) ---------------
    short8 bAh, bAl, bBh, bBl;
    float wA, wB;
    f32x4 dA[ROWTILES], dB[ROWTILES];

    READB(0, bAh, bAl, wA);
    READB(1, bBh, bBl, wB);
    MFMAJT(bAh, bAl, dA);

#pragma unroll
    for (int k = 0; k < NT; k += 2) {
        float wAn = wA, wBn = wB;
        if (k + 2 < NT) READB(k + 2, bAh, bAl, wAn);
        MFMAJT(bBh, bBl, dB);          // jt k+1 issues to matrix pipe...
        EPILOG(dA, wA);                // ...while jt k's epilogue runs on VALU
        wA = wAn;
        if (k + 3 < NT) READB(k + 3, bBh, bBl, wBn);
        if (k + 2 < NT) MFMAJT(bAh, bAl, dA);  // jt k+2 issues...
        EPILOG(dB, wB);                        // ...under jt k+1's epilogue
        wB = wBn;
    }
#undef READB
#undef MFMAJT
#undef EPILOG

    // ---- reduce over the 16 columns (lane bits 0..3) -----------------------
#pragma unroll
    for (int t = 0; t < ROWTILES; ++t)
#pragma unroll
        for (int rr = 0; rr < 4; ++rr) {
            float v = acc[t][rr];
            v += __shfl_xor(v, 1, 64);
            v += __shfl_xor(v, 2, 64);
            v += __shfl_xor(v, 4, 64);
            v += __shfl_xor(v, 8, 64);
            acc[t][rr] = v;
        }
    // ---- epilogue: apply 2^Bx (row-only) once, store float4 ----------------
    if (l15 == 0) {
#pragma unroll
        for (int t = 0; t < ROWTILES; ++t) {
            float4 bxv = *(const float4*)&Bx[rowbase + t * 16 + lhi * 4];
            f32x4 o;
            o[0] = acc[t][0] * __builtin_amdgcn_exp2f(bxv.x);
            o[1] = acc[t][1] * __builtin_amdgcn_exp2f(bxv.y);
            o[2] = acc[t][2] * __builtin_amdgcn_exp2f(bxv.z);
            o[3] = acc[t][3] * __builtin_amdgcn_exp2f(bxv.w);
            *(f32x4*)&part[(size_t)slice * NN + rowbase + t * 16 + lhi * 4] = o;
        }
    }
}

template <int MS>
__global__ __launch_bounds__(256) void reduce_kern(const float* __restrict__ part,
                                                   float* __restrict__ out) {
    int i = blockIdx.x * 256 + threadIdx.x;
    float s = 0.f;
#pragma unroll
    for (int k = 0; k < MS; ++k) s += part[(size_t)k * NN + i];
    out[i] = s;
}

// ---------------------------------------------------------------------------
// Fallback (round-1 VALU path) in case ws_size is too small.
// ---------------------------------------------------------------------------
__global__ __launch_bounds__(256) void wkern(const float* __restrict__ C,
                                             const float* __restrict__ alphas,
                                             const float* __restrict__ sigma,
                                             float* __restrict__ w) {
    int j = blockIdx.x * 256 + threadIdx.x;
    if (j >= MM) return;
    float g = sigma[0];
    float inv_g2 = 1.0f / (g * g);
    const float4* cp = (const float4*)(C + (size_t)j * DD);
    float y2 = 0.f;
#pragma unroll
    for (int q = 0; q < DD / 4; ++q) {
        float4 v = cp[q];
        y2 = fmaf(v.x, v.x, y2);
        y2 = fmaf(v.y, v.y, y2);
        y2 = fmaf(v.z, v.z, y2);
        y2 = fmaf(v.w, v.w, y2);
    }
    w[j] = alphas[j] * exp2f(-0.5f * inv_g2 * 1.44269504088896340736f * y2);
}

__global__ __launch_bounds__(128) void rbf_valu(const float* __restrict__ X,
                                                const float* __restrict__ C,
                                                const float* __restrict__ w,
                                                const float* __restrict__ sigma,
                                                float* __restrict__ out) {
    const int row = blockIdx.x * 128 + threadIdx.x;
    const float g = sigma[0];
    const float A = 1.44269504088896340736f / (g * g);
    float x[DD];
    const float4* xp = (const float4*)(X + (size_t)row * DD);
#pragma unroll
    for (int q = 0; q < DD / 4; ++q) {
        float4 v = xp[q];
        x[4 * q + 0] = v.x; x[4 * q + 1] = v.y;
        x[4 * q + 2] = v.z; x[4 * q + 3] = v.w;
    }
    float x2 = 0.f;
#pragma unroll
    for (int d = 0; d < DD; ++d) x2 = fmaf(x[d], x[d], x2);
    const float B = -0.5f * A * x2;
    float acc = 0.f;
#pragma unroll 2
    for (int j = 0; j < MM; ++j) {
        const float* cj = C + (size_t)j * DD;
        float d0 = 0.f, d1 = 0.f, d2 = 0.f, d3 = 0.f;
#pragma unroll
        for (int d = 0; d < DD; d += 4) {
            d0 = fmaf(cj[d + 0], x[d + 0], d0);
            d1 = fmaf(cj[d + 1], x[d + 1], d1);
            d2 = fmaf(cj[d + 2], x[d + 2], d2);
            d3 = fmaf(cj[d + 3], x[d + 3], d3);
        }
        float dot = (d0 + d1) + (d2 + d3);
        acc = fmaf(w[j], exp2f(fmaf(dot, A, B)), acc);
    }
    out[row] = acc;
}

extern "C" void kernel_launch(void* const* d_in, const int* in_sizes, int n_in,
                              void* d_out, int out_size, void* d_ws, size_t ws_size,
                              hipStream_t stream) {
    const float* X  = (const float*)d_in[0];
    const float* C  = (const float*)d_in[1];
    const float* al = (const float*)d_in[2];
    const float* sg = (const float*)d_in[3];
    float* out = (float*)d_out;

    // Workspace layout (all 16B aligned).
    size_t off = 0;
    unsigned short* Xh = (unsigned short*)((char*)d_ws + off); off += (size_t)NN * DD * 2;
    unsigned short* Xl = (unsigned short*)((char*)d_ws + off); off += (size_t)NN * DD * 2;
    unsigned short* Ch = (unsigned short*)((char*)d_ws + off); off += (size_t)MM * DD * 2;
    unsigned short* Cl = (unsigned short*)((char*)d_ws + off); off += (size_t)MM * DD * 2;
    float* Bx = (float*)((char*)d_ws + off); off += (size_t)NN * 4;
    float* w  = (float*)((char*)d_ws + off); off += (size_t)MM * 4;
    float* part = (float*)((char*)d_ws + off);
    const size_t base = off;

    const size_t need32 = base + (size_t)32 * NN * 4;
    const size_t need8  = base + (size_t)8 * NN * 4;

    if (ws_size >= need8) {
        prep_kern<<<(NN + MM) * 4 / 256, 256, 0, stream>>>(X, C, al, sg, Xh, Xl, Ch, Cl, Bx, w);
        if (ws_size >= need32) {
            dim3 grid(NN / (WAVES * 16 * ROWTILES), 32);
            rbf_mfma_lds<32><<<grid, 64 * WAVES, 0, stream>>>(Xh, Xl, Ch, Cl, Bx, w, part);
            reduce_kern<32><<<NN / 256, 256, 0, stream>>>(part, out);
        } else {
            dim3 grid(NN / (WAVES * 16 * ROWTILES), 8);
            rbf_mfma_lds<8><<<grid, 64 * WAVES, 0, stream>>>(Xh, Xl, Ch, Cl, Bx, w, part);
            reduce_kern<8><<<NN / 256, 256, 0, stream>>>(part, out);
        }
    } else {
        // Fallback: fp32 VALU path, needs only 16 KB for w.
        float* wf = (float*)d_ws;
        wkern<<<MM / 256, 256, 0, stream>>>(C, al, sg, wf);
        rbf_valu<<<NN / 128, 128, 0, stream>>>(X, C, wf, sg, out);
    }
}

// Round 13
// 40.012 us; speedup vs baseline: 1.5602x; 1.0562x over previous
//
#include <hip/hip_runtime.h>

#define NN 32768
#define MM 4096
#define DD 32

typedef short short8 __attribute__((ext_vector_type(8)));
typedef float f32x4 __attribute__((ext_vector_type(4)));

#define ROWTILES 4     // 16-row MFMA tiles per wave -> 64 rows/wave
#define WAVES 4        // waves per block -> 256 rows/block

__device__ __forceinline__ unsigned short f2bf(float f) {
    unsigned u = __float_as_uint(f);
    unsigned r = 0x7FFFu + ((u >> 16) & 1u);
    return (unsigned short)((u + r) >> 16);
}
__device__ __forceinline__ float bf2f(unsigned short h) {
    return __uint_as_float(((unsigned)h) << 16);
}

// ---------------------------------------------------------------------------
// Prep (element-parallel): 4 lanes per row, each handling 8 elements.
// X is PRE-SCALED by LA = log2(e)/g^2 before the bf16 hi/lo split.
// Bx_i = -0.5*LA*||x_i||^2 ; w_j = alpha_j * 2^(-0.5*LA*||y_j||^2).
// ---------------------------------------------------------------------------
__global__ __launch_bounds__(256) void prep_kern(
    const float* __restrict__ X, const float* __restrict__ C,
    const float* __restrict__ alphas, const float* __restrict__ sigma,
    unsigned short* __restrict__ Xh, unsigned short* __restrict__ Xl,
    unsigned short* __restrict__ Ch, unsigned short* __restrict__ Cl,
    float* __restrict__ Bx, float* __restrict__ w)
{
    const int i = blockIdx.x * 256 + threadIdx.x;   // (NN+MM)*4 total
    const int row = i >> 2;
    const int q = i & 3;
    const float g = sigma[0];
    const float LA = 1.44269504088896340736f / (g * g);

    const bool isX = (row < NN);
    const int crow = isX ? row : (row - NN);
    const float* src = (isX ? X + (size_t)row * DD : C + (size_t)crow * DD) + q * 8;
    unsigned short* dh = (isX ? Xh + (size_t)row * DD : Ch + (size_t)crow * DD) + q * 8;
    unsigned short* dl = (isX ? Xl + (size_t)row * DD : Cl + (size_t)crow * DD) + q * 8;
    const float scale = isX ? LA : 1.0f;

    float4 a = ((const float4*)src)[0];
    float4 b = ((const float4*)src)[1];
    float vv[8] = {a.x, a.y, a.z, a.w, b.x, b.y, b.z, b.w};
    float s2 = 0.f;
    short8 hv, lv;
#pragma unroll
    for (int e = 0; e < 8; ++e) {
        float v = vv[e];
        s2 = fmaf(v, v, s2);
        float sv = v * scale;
        unsigned short h = f2bf(sv);
        hv[e] = (short)h;
        lv[e] = (short)f2bf(sv - bf2f(h));
    }
    *(short8*)dh = hv;
    *(short8*)dl = lv;

    // 4-lane row-sum (lanes row*4 .. row*4+3 are contiguous in the wave)
    s2 += __shfl_xor(s2, 1, 64);
    s2 += __shfl_xor(s2, 2, 64);
    if (q == 0) {
        float bb = -0.5f * LA * s2;
        if (isX) Bx[row] = bb;
        else     w[crow] = alphas[crow] * exp2f(bb);
    }
}

// ---------------------------------------------------------------------------
// Main: R10 carrier + PHASE-STAGGER + setprio to overlap MFMA/VALU pipes.
// Cycle model (m06-derived 19.4cy/SIMD per 16x16x32 MFMA + R6 PMC fit):
// per SIMD the kernel owes MFMA 30k cy + VALU 44k cy (exp@16cy dominates);
// R6 measured wall = 74k cy = exact serial sum -> waves are PHASE-LOCKED
// (identical bodies, no desync source): all resident waves MFMA together,
// then exp together, each pipe idling half the time.
// Fix: (1) odd waves run a ~300cy dummy dependent-exp chain pre-loop
// (asm-kept-alive), a persistent half-body offset so even waves' MFMA phase
// overlaps odd waves' exp phase; (2) s_setprio(1) around the MFMA cluster
// (T5: pays only with phase diversity, which (1) creates).
// Numerics identical to R10: acc = sum_j wj*2^t, 2^Bx applied at store.
// ---------------------------------------------------------------------------
template <int MS>
__global__ __launch_bounds__(256, 4) void rbf_mfma_lds(
    const unsigned short* __restrict__ Xh, const unsigned short* __restrict__ Xl,
    const unsigned short* __restrict__ Ch, const unsigned short* __restrict__ Cl,
    const float* __restrict__ Bx, const float* __restrict__ w,
    float* __restrict__ part)
{
    constexpr int MPER = MM / MS;
    constexpr int NT = MPER / 16;
    __shared__ unsigned short sCh[MPER * DD];
    __shared__ unsigned short sCl[MPER * DD];
    __shared__ float sw[MPER];

    const int tid = threadIdx.x;
    const int wave = tid >> 6;
    const int lane = tid & 63;
    const int l15 = lane & 15;
    const int lhi = lane >> 4;
    const int rowbase = (blockIdx.x * WAVES + wave) * (16 * ROWTILES);
    const int slice = blockIdx.y;
    const int j0 = slice * MPER;

    const char* lh = (const char*)sCh;
    const char* ll = (const char*)sCl;

    // ---- stage C slice (hi+lo) and w slice into LDS, linear & vectorized ---
    {
        const float4* gh = (const float4*)(Ch + (size_t)j0 * DD);
        const float4* gl = (const float4*)(Cl + (size_t)j0 * DD);
        constexpr int NV = MPER * DD / 8;  // 16B chunks per slab
        for (int o = tid; o < NV; o += 256) {
            ((float4*)sCh)[o] = gh[o];
            ((float4*)sCl)[o] = gl[o];
        }
        if (tid < MPER) sw[tid] = w[j0 + tid];
    }

    // ---- A fragments (hi/lo), loaded while staging is in flight ------------
    short8 ah[ROWTILES], al[ROWTILES];
#pragma unroll
    for (int t = 0; t < ROWTILES; ++t) {
        int r = rowbase + t * 16 + l15;
        ah[t] = *(const short8*)(Xh + (size_t)r * DD + lhi * 8);
        al[t] = *(const short8*)(Xl + (size_t)r * DD + lhi * 8);
    }

    f32x4 acc[ROWTILES];
#pragma unroll
    for (int t = 0; t < ROWTILES; ++t) acc[t] = (f32x4){0.f, 0.f, 0.f, 0.f};

    __syncthreads();

    // ---- phase-stagger: odd waves delayed ~half a jt body (~300cy) ---------
    if (wave & 1) {
        float z = (float)lane * 1e-20f;
#pragma unroll
        for (int q = 0; q < 10; ++q) z = __builtin_amdgcn_exp2f(z);
        asm volatile("" :: "v"(z));  // keep the chain alive (no DCE)
    }

    const int lbase = l15 * 64 + lhi * 16;
    const f32x4 kZero = {0.f, 0.f, 0.f, 0.f};

    // ---- main loop: immediate-offset ds_reads, prio'd 3-MFMA, exp ----------
#pragma unroll 2
    for (int jt = 0; jt < NT; ++jt) {
        short8 bh = *(const short8*)(lh + lbase + jt * 1024);
        short8 bl = *(const short8*)(ll + lbase + jt * 1024);
        float wj = sw[jt * 16 + l15];
        f32x4 d[ROWTILES];
        __builtin_amdgcn_s_setprio(1);
#pragma unroll
        for (int t = 0; t < ROWTILES; ++t) {
            f32x4 dd;
            dd = __builtin_amdgcn_mfma_f32_16x16x32_bf16(ah[t], bl, kZero, 0, 0, 0);
            dd = __builtin_amdgcn_mfma_f32_16x16x32_bf16(al[t], bh, dd, 0, 0, 0);
            dd = __builtin_amdgcn_mfma_f32_16x16x32_bf16(ah[t], bh, dd, 0, 0, 0);
            d[t] = dd;
        }
        __builtin_amdgcn_s_setprio(0);
#pragma unroll
        for (int t = 0; t < ROWTILES; ++t)
#pragma unroll
            for (int rr = 0; rr < 4; ++rr)
                acc[t][rr] = fmaf(wj, __builtin_amdgcn_exp2f(d[t][rr]), acc[t][rr]);
    }

    // ---- reduce over the 16 columns (lane bits 0..3) -----------------------
#pragma unroll
    for (int t = 0; t < ROWTILES; ++t)
#pragma unroll
        for (int rr = 0; rr < 4; ++rr) {
            float v = acc[t][rr];
            v += __shfl_xor(v, 1, 64);
            v += __shfl_xor(v, 2, 64);
            v += __shfl_xor(v, 4, 64);
            v += __shfl_xor(v, 8, 64);
            acc[t][rr] = v;
        }
    // ---- epilogue: apply 2^Bx (row-only) once, store float4 ----------------
    if (l15 == 0) {
#pragma unroll
        for (int t = 0; t < ROWTILES; ++t) {
            float4 bxv = *(const float4*)&Bx[rowbase + t * 16 + lhi * 4];
            f32x4 o;
            o[0] = acc[t][0] * __builtin_amdgcn_exp2f(bxv.x);
            o[1] = acc[t][1] * __builtin_amdgcn_exp2f(bxv.y);
            o[2] = acc[t][2] * __builtin_amdgcn_exp2f(bxv.z);
            o[3] = acc[t][3] * __builtin_amdgcn_exp2f(bxv.w);
            *(f32x4*)&part[(size_t)slice * NN + rowbase + t * 16 + lhi * 4] = o;
        }
    }
}

template <int MS>
__global__ __launch_bounds__(256) void reduce_kern(const float* __restrict__ part,
                                                   float* __restrict__ out) {
    int i = blockIdx.x * 256 + threadIdx.x;
    float s = 0.f;
#pragma unroll
    for (int k = 0; k < MS; ++k) s += part[(size_t)k * NN + i];
    out[i] = s;
}

// ---------------------------------------------------------------------------
// Fallback (round-1 VALU path) in case ws_size is too small.
// ---------------------------------------------------------------------------
__global__ __launch_bounds__(256) void wkern(const float* __restrict__ C,
                                             const float* __restrict__ alphas,
                                             const float* __restrict__ sigma,
                                             float* __restrict__ w) {
    int j = blockIdx.x * 256 + threadIdx.x;
    if (j >= MM) return;
    float g = sigma[0];
    float inv_g2 = 1.0f / (g * g);
    const float4* cp = (const float4*)(C + (size_t)j * DD);
    float y2 = 0.f;
#pragma unroll
    for (int q = 0; q < DD / 4; ++q) {
        float4 v = cp[q];
        y2 = fmaf(v.x, v.x, y2);
        y2 = fmaf(v.y, v.y, y2);
        y2 = fmaf(v.z, v.z, y2);
        y2 = fmaf(v.w, v.w, y2);
    }
    w[j] = alphas[j] * exp2f(-0.5f * inv_g2 * 1.44269504088896340736f * y2);
}

__global__ __launch_bounds__(128) void rbf_valu(const float* __restrict__ X,
                                                const float* __restrict__ C,
                                                const float* __restrict__ w,
                                                const float* __restrict__ sigma,
                                                float* __restrict__ out) {
    const int row = blockIdx.x * 128 + threadIdx.x;
    const float g = sigma[0];
    const float A = 1.44269504088896340736f / (g * g);
    float x[DD];
    const float4* xp = (const float4*)(X + (size_t)row * DD);
#pragma unroll
    for (int q = 0; q < DD / 4; ++q) {
        float4 v = xp[q];
        x[4 * q + 0] = v.x; x[4 * q + 1] = v.y;
        x[4 * q + 2] = v.z; x[4 * q + 3] = v.w;
    }
    float x2 = 0.f;
#pragma unroll
    for (int d = 0; d < DD; ++d) x2 = fmaf(x[d], x[d], x2);
    const float B = -0.5f * A * x2;
    float acc = 0.f;
#pragma unroll 2
    for (int j = 0; j < MM; ++j) {
        const float* cj = C + (size_t)j * DD;
        float d0 = 0.f, d1 = 0.f, d2 = 0.f, d3 = 0.f;
#pragma unroll
        for (int d = 0; d < DD; d += 4) {
            d0 = fmaf(cj[d + 0], x[d + 0], d0);
            d1 = fmaf(cj[d + 1], x[d + 1], d1);
            d2 = fmaf(cj[d + 2], x[d + 2], d2);
            d3 = fmaf(cj[d + 3], x[d + 3], d3);
        }
        float dot = (d0 + d1) + (d2 + d3);
        acc = fmaf(w[j], exp2f(fmaf(dot, A, B)), acc);
    }
    out[row] = acc;
}

extern "C" void kernel_launch(void* const* d_in, const int* in_sizes, int n_in,
                              void* d_out, int out_size, void* d_ws, size_t ws_size,
                              hipStream_t stream) {
    const float* X  = (const float*)d_in[0];
    const float* C  = (const float*)d_in[1];
    const float* al = (const float*)d_in[2];
    const float* sg = (const float*)d_in[3];
    float* out = (float*)d_out;

    // Workspace layout (all 16B aligned).
    size_t off = 0;
    unsigned short* Xh = (unsigned short*)((char*)d_ws + off); off += (size_t)NN * DD * 2;
    unsigned short* Xl = (unsigned short*)((char*)d_ws + off); off += (size_t)NN * DD * 2;
    unsigned short* Ch = (unsigned short*)((char*)d_ws + off); off += (size_t)MM * DD * 2;
    unsigned short* Cl = (unsigned short*)((char*)d_ws + off); off += (size_t)MM * DD * 2;
    float* Bx = (float*)((char*)d_ws + off); off += (size_t)NN * 4;
    float* w  = (float*)((char*)d_ws + off); off += (size_t)MM * 4;
    float* part = (float*)((char*)d_ws + off);
    const size_t base = off;

    const size_t need32 = base + (size_t)32 * NN * 4;
    const size_t need8  = base + (size_t)8 * NN * 4;

    if (ws_size >= need8) {
        prep_kern<<<(NN + MM) * 4 / 256, 256, 0, stream>>>(X, C, al, sg, Xh, Xl, Ch, Cl, Bx, w);
        if (ws_size >= need32) {
            dim3 grid(NN / (WAVES * 16 * ROWTILES), 32);
            rbf_mfma_lds<32><<<grid, 64 * WAVES, 0, stream>>>(Xh, Xl, Ch, Cl, Bx, w, part);
            reduce_kern<32><<<NN / 256, 256, 0, stream>>>(part, out);
        } else {
            dim3 grid(NN / (WAVES * 16 * ROWTILES), 8);
            rbf_mfma_lds<8><<<grid, 64 * WAVES, 0, stream>>>(Xh, Xl, Ch, Cl, Bx, w, part);
            reduce_kern<8><<<NN / 256, 256, 0, stream>>>(part, out);
        }
    } else {
        // Fallback: fp32 VALU path, needs only 16 KB for w.
        float* wf = (float*)d_ws;
        wkern<<<MM / 256, 256, 0, stream>>>(C, al, sg, wf);
        rbf_valu<<<NN / 128, 128, 0, stream>>>(X, C, wf, sg, out);
    }
}